// Round 5
// baseline (1299.700 us; speedup 1.0000x reference)
//
#include <hip/hip_runtime.h>
#include <stdint.h>

// Problem geometry (fixed by the reference).
#define M_DIM 4096      // BATCH * SEQ
#define N_DIM 16384     // OUT_FEATURES
#define K_DIM 4096      // IN_FEATURES

#define BM 256
#define BN 256
#define BK 64
#define NT (K_DIM / BK)   // 64 K-tiles

typedef __attribute__((ext_vector_type(8))) short bf16x8;
typedef __attribute__((ext_vector_type(4))) float f32x4;

// ---------- helpers ----------

// fp32 -> bf16 bits, round-to-nearest-even
static __device__ __forceinline__ unsigned short f2bf(float f) {
    unsigned int u = __float_as_uint(f);
    return (unsigned short)((u + 0x7FFFu + ((u >> 16) & 1u)) >> 16);
}

typedef __attribute__((address_space(3))) void lds_void_t;
typedef const __attribute__((address_space(1))) void gbl_void_t;

// async global->LDS, 16B per lane. LDS dest is wave-uniform base; HW adds lane*16.
static __device__ __forceinline__ void gload_lds16(const void* g, void* s) {
    __builtin_amdgcn_global_load_lds((gbl_void_t*)g, (lds_void_t*)s, 16, 0, 0);
}

static __device__ __forceinline__ f32x4 mfma16(bf16x8 a, bf16x8 b, f32x4 c) {
    return __builtin_amdgcn_mfma_f32_16x16x32_bf16(a, b, c, 0, 0, 0);
}

#define BAR   __builtin_amdgcn_s_barrier()
#define LGKM0 asm volatile("s_waitcnt lgkmcnt(0)" ::: "memory")

// ---------- conversion kernels ----------

__global__ void cvt_x_kernel(const float* __restrict__ x,
                             unsigned short* __restrict__ xb, int n8) {
    int i = blockIdx.x * blockDim.x + threadIdx.x;
    if (i >= n8) return;
    const float4 v0 = ((const float4*)x)[2 * i + 0];
    const float4 v1 = ((const float4*)x)[2 * i + 1];
    uint4 pk;
    pk.x = (unsigned)f2bf(v0.x) | ((unsigned)f2bf(v0.y) << 16);
    pk.y = (unsigned)f2bf(v0.z) | ((unsigned)f2bf(v0.w) << 16);
    pk.z = (unsigned)f2bf(v1.x) | ((unsigned)f2bf(v1.y) << 16);
    pk.w = (unsigned)f2bf(v1.z) | ((unsigned)f2bf(v1.w) << 16);
    ((uint4*)xb)[i] = pk;
}

// weight fp32 [N][K] -> 2:4-masked bf16 [N][K]. Mask = JAX stable-argsort rank>=2.
__global__ void cvt_w_kernel(const float* __restrict__ w,
                             unsigned short* __restrict__ wb, int ngroups) {
    int g = blockIdx.x * blockDim.x + threadIdx.x;
    if (g >= ngroups) return;
    const float4 v = ((const float4*)w)[g];
    float a0 = fabsf(v.x), a1 = fabsf(v.y), a2 = fabsf(v.z), a3 = fabsf(v.w);
    int r0 = (a1 < a0) + (a2 < a0) + (a3 < a0);
    int r1 = (a0 < a1) + (a2 < a1) + (a3 < a1) + (a0 == a1);
    int r2 = (a0 < a2) + (a1 < a2) + (a3 < a2) + (a0 == a2) + (a1 == a2);
    int r3 = (a0 < a3) + (a1 < a3) + (a2 < a3) + (a0 == a3) + (a1 == a3) + (a2 == a3);
    unsigned short o0 = (r0 >= 2) ? f2bf(v.x) : (unsigned short)0;
    unsigned short o1 = (r1 >= 2) ? f2bf(v.y) : (unsigned short)0;
    unsigned short o2 = (r2 >= 2) ? f2bf(v.z) : (unsigned short)0;
    unsigned short o3 = (r3 >= 2) ? f2bf(v.w) : (unsigned short)0;
    uint2 pk;
    pk.x = (unsigned)o0 | ((unsigned)o1 << 16);
    pk.y = (unsigned)o2 | ((unsigned)o3 << 16);
    ((uint2*)wb)[g] = pk;
}

// ---------- main GEMM: C[M][N] = A[M][K] * B[N][K]^T + bias ----------
// 256x256 tile, 8 waves (2Mx4N), BK=64, 8-phase schedule (2 tiles/iter),
// counted vmcnt(8) at tile boundaries (T4), chunk-XOR LDS swizzle (T2),
// setprio around MFMA clusters (T5), 2D-chunked XCD-aware block mapping (T1).

__global__ __launch_bounds__(512, 2)
void gemm_bt_kernel(const unsigned short* __restrict__ A,   // bf16 bits [M][K]
                    const unsigned short* __restrict__ B,   // bf16 bits [N][K]
                    const float* __restrict__ bias,
                    float* __restrict__ C) {
    __shared__ unsigned short As[2][BM][BK];   // 64 KB (double-buffered)
    __shared__ unsigned short Bs[2][BN][BK];   // 64 KB

    const int tid  = threadIdx.x;
    const int lane = tid & 63;
    const int wid  = tid >> 6;          // 0..7
    const int wm   = (wid >> 2) * 128;  // wave M offset: 0 / 128
    const int wn   = (wid & 3) * 64;    // wave N offset: 0..192

    // XCD-aware 2D-chunked mapping: 1024 wgs = 16(M) x 64(N) tiles; each XCD
    // gets a contiguous 16x8 tile block (48MB footprint: fits L3 partition).
    const int xcd  = blockIdx.x & 7;
    const int loc  = blockIdx.x >> 3;       // 0..127
    const int tm   = (loc >> 3) * BM;       // 16 M-tiles
    const int tn   = (xcd * 8 + (loc & 7)) * BN;  // 64 N-tiles

    // staging: lane -> (sub-row, logical k-chunk).  Swizzle: phys chunk
    // p = c ^ (row&7); gload writes linearly so the SOURCE is pre-swizzled.
    const int sub  = lane >> 3;           // 0..7
    const int clog = (lane & 7) ^ sub;    // logical 16B chunk this lane fetches

    // per-quarter global source pointers (row fixed; K advances per tile)
    const unsigned short* pA[4];
    const unsigned short* pB[4];
#pragma unroll
    for (int q = 0; q < 4; ++q) {
        pA[q] = A + (size_t)(tm + q * 64 + wid * 8 + sub) * K_DIM + clog * 8;
        pB[q] = B + (size_t)(tn + q * 64 + wid * 8 + sub) * K_DIM + clog * 8;
    }

    const int frow = lane & 15;           // fragment row (A) / col (B,C)
    const int fk   = lane >> 4;           // 0..3
    const int pc0  = (0 + fk) ^ (frow & 7);   // phys chunk, kk=0
    const int pc1  = (4 + fk) ^ (frow & 7);   // phys chunk, kk=1

    f32x4 acc[8][4] = {};

    // -------- prologue: stage K-tiles 0 and 1 --------
#pragma unroll
    for (int q = 0; q < 4; ++q) {
        gload_lds16(pA[q], &As[0][q * 64 + wid * 8][0]);
        gload_lds16(pB[q], &Bs[0][q * 64 + wid * 8][0]);
    }
#pragma unroll
    for (int q = 0; q < 4; ++q) {
        gload_lds16(pA[q] + BK, &As[1][q * 64 + wid * 8][0]);
        gload_lds16(pB[q] + BK, &Bs[1][q * 64 + wid * 8][0]);
    }
    asm volatile("s_waitcnt vmcnt(8)" ::: "memory");   // tile 0 landed; tile 1 in flight
    BAR;

    // Per tile: 4 phases x {ds_read subtile | stage pieces | BAR | lgkm(0) |
    // setprio(1) 16xMFMA setprio(0) | BAR}.  Reads front-loaded in phases 1-2;
    // stage(t+2) pieces issued in phases 2-4 only into regions fully read a
    // phase earlier.  vmcnt(8) ONLY at tile end (keeps next tile's 8 loads in
    // flight across barriers).
#define TILE_STEP(BUFC)                                                         \
  {                                                                             \
    const int  tt      = t + (BUFC);                                            \
    const bool dostage = (tt + 2 < NT);                                         \
    const int  koff    = (tt + 2) * BK;                                         \
    bf16x8 alo[4][2], ahi[4][2], blo[2][2], bhi[2][2];                          \
    /* ---- phase 1: read A i0-3 + B j0-1; MFMA Q0 ---- */                      \
    _Pragma("unroll")                                                           \
    for (int i = 0; i < 4; ++i) {                                               \
      alo[i][0] = *(const bf16x8*)&As[BUFC][wm + i * 16 + frow][pc0 * 8];       \
      alo[i][1] = *(const bf16x8*)&As[BUFC][wm + i * 16 + frow][pc1 * 8];       \
    }                                                                           \
    _Pragma("unroll")                                                           \
    for (int j = 0; j < 2; ++j) {                                               \
      blo[j][0] = *(const bf16x8*)&Bs[BUFC][wn + j * 16 + frow][pc0 * 8];       \
      blo[j][1] = *(const bf16x8*)&Bs[BUFC][wn + j * 16 + frow][pc1 * 8];       \
    }                                                                           \
    BAR; LGKM0;                                                                 \
    __builtin_amdgcn_s_setprio(1);                                              \
    _Pragma("unroll")                                                           \
    for (int i = 0; i < 4; ++i)                                                 \
      _Pragma("unroll")                                                         \
      for (int j = 0; j < 2; ++j) {                                             \
        acc[i][j] = mfma16(alo[i][0], blo[j][0], acc[i][j]);                    \
        acc[i][j] = mfma16(alo[i][1], blo[j][1], acc[i][j]);                    \
      }                                                                         \
    __builtin_amdgcn_s_setprio(0);                                              \
    BAR;                                                                        \
    /* ---- phase 2: read A i4-7 + B j2-3; stage A-q0,A-q2(t+2); MFMA Q1 ---- */\
    _Pragma("unroll")                                                           \
    for (int i = 0; i < 4; ++i) {                                               \
      ahi[i][0] = *(const bf16x8*)&As[BUFC][wm + 64 + i * 16 + frow][pc0 * 8];  \
      ahi[i][1] = *(const bf16x8*)&As[BUFC][wm + 64 + i * 16 + frow][pc1 * 8];  \
    }                                                                           \
    _Pragma("unroll")                                                           \
    for (int j = 0; j < 2; ++j) {                                               \
      bhi[j][0] = *(const bf16x8*)&Bs[BUFC][wn + 32 + j * 16 + frow][pc0 * 8];  \
      bhi[j][1] = *(const bf16x8*)&Bs[BUFC][wn + 32 + j * 16 + frow][pc1 * 8];  \
    }                                                                           \
    if (dostage) {                                                              \
      gload_lds16(pA[0] + koff, &As[BUFC][0 * 64 + wid * 8][0]);                \
      gload_lds16(pA[2] + koff, &As[BUFC][2 * 64 + wid * 8][0]);                \
    }                                                                           \
    BAR; LGKM0;                                                                 \
    __builtin_amdgcn_s_setprio(1);                                              \
    _Pragma("unroll")                                                           \
    for (int i = 0; i < 4; ++i)                                                 \
      _Pragma("unroll")                                                         \
      for (int j = 0; j < 2; ++j) {                                             \
        acc[i][2 + j] = mfma16(alo[i][0], bhi[j][0], acc[i][2 + j]);            \
        acc[i][2 + j] = mfma16(alo[i][1], bhi[j][1], acc[i][2 + j]);            \
      }                                                                         \
    __builtin_amdgcn_s_setprio(0);                                              \
    BAR;                                                                        \
    /* ---- phase 3: stage A-q1,A-q3,B-q0(t+2); MFMA Q2 ---- */                 \
    if (dostage) {                                                              \
      gload_lds16(pA[1] + koff, &As[BUFC][1 * 64 + wid * 8][0]);                \
      gload_lds16(pA[3] + koff, &As[BUFC][3 * 64 + wid * 8][0]);                \
      gload_lds16(pB[0] + koff, &Bs[BUFC][0 * 64 + wid * 8][0]);                \
    }                                                                           \
    BAR; LGKM0;                                                                 \
    __builtin_amdgcn_s_setprio(1);                                              \
    _Pragma("unroll")                                                           \
    for (int i = 0; i < 4; ++i)                                                 \
      _Pragma("unroll")                                                         \
      for (int j = 0; j < 2; ++j) {                                             \
        acc[4 + i][j] = mfma16(ahi[i][0], blo[j][0], acc[4 + i][j]);            \
        acc[4 + i][j] = mfma16(ahi[i][1], blo[j][1], acc[4 + i][j]);            \
      }                                                                         \
    __builtin_amdgcn_s_setprio(0);                                              \
    BAR;                                                                        \
    /* ---- phase 4: stage B-q1,B-q2,B-q3(t+2); MFMA Q3; vmcnt ---- */          \
    if (dostage) {                                                              \
      gload_lds16(pB[1] + koff, &Bs[BUFC][1 * 64 + wid * 8][0]);                \
      gload_lds16(pB[2] + koff, &Bs[BUFC][2 * 64 + wid * 8][0]);                \
      gload_lds16(pB[3] + koff, &Bs[BUFC][3 * 64 + wid * 8][0]);                \
    }                                                                           \
    BAR; LGKM0;                                                                 \
    __builtin_amdgcn_s_setprio(1);                                              \
    _Pragma("unroll")                                                           \
    for (int i = 0; i < 4; ++i)                                                 \
      _Pragma("unroll")                                                         \
      for (int j = 0; j < 2; ++j) {                                             \
        acc[4 + i][2 + j] = mfma16(ahi[i][0], bhi[j][0], acc[4 + i][2 + j]);    \
        acc[4 + i][2 + j] = mfma16(ahi[i][1], bhi[j][1], acc[4 + i][2 + j]);    \
      }                                                                         \
    __builtin_amdgcn_s_setprio(0);                                              \
    if (dostage) { asm volatile("s_waitcnt vmcnt(8)" ::: "memory"); }           \
    else         { asm volatile("s_waitcnt vmcnt(0)" ::: "memory"); }           \
    BAR;                                                                        \
  }

    for (int t = 0; t < NT; t += 2) {
        TILE_STEP(0)
        TILE_STEP(1)
    }
#undef TILE_STEP

    // epilogue: C/D layout col = lane&15, row = (lane>>4)*4 + reg
    const int orow0 = tm + wm;
    const int ocol0 = tn + wn;
#pragma unroll
    for (int j = 0; j < 4; ++j) {
        int col = ocol0 + j * 16 + frow;
        float bj = bias[col];
#pragma unroll
        for (int i = 0; i < 8; ++i) {
            f32x4 v = acc[i][j];
            int rbase = orow0 + i * 16 + fk * 4;
#pragma unroll
            for (int r = 0; r < 4; ++r)
                C[(size_t)(rbase + r) * N_DIM + col] = v[r] + bj;
        }
    }
}

// ---------- fp32 fallback (only if ws too small) ----------
__global__ void naive_kernel(const float* __restrict__ x, const float* __restrict__ w,
                             const float* __restrict__ bias, float* __restrict__ out) {
    int n  = blockIdx.x;
    int m  = blockIdx.y * 256 + threadIdx.x;
    const float4* xr = (const float4*)(x + (size_t)m * K_DIM);
    const float4* wr = (const float4*)(w + (size_t)n * K_DIM);
    float s = 0.f;
    for (int g = 0; g < K_DIM / 4; ++g) {
        float4 wv = wr[g];
        float4 xv = xr[g];
        float a0 = fabsf(wv.x), a1 = fabsf(wv.y), a2 = fabsf(wv.z), a3 = fabsf(wv.w);
        int r0 = (a1 < a0) + (a2 < a0) + (a3 < a0);
        int r1 = (a0 < a1) + (a2 < a1) + (a3 < a1) + (a0 == a1);
        int r2 = (a0 < a2) + (a1 < a2) + (a3 < a2) + (a0 == a2) + (a1 == a2);
        int r3 = (a0 < a3) + (a1 < a3) + (a2 < a3) + (a0 == a3) + (a1 == a3) + (a2 == a3);
        if (r0 >= 2) s += xv.x * wv.x;
        if (r1 >= 2) s += xv.y * wv.y;
        if (r2 >= 2) s += xv.z * wv.z;
        if (r3 >= 2) s += xv.w * wv.w;
    }
    out[(size_t)m * N_DIM + n] = s + bias[n];
}

// ---------- launch ----------
extern "C" void kernel_launch(void* const* d_in, const int* in_sizes, int n_in,
                              void* d_out, int out_size, void* d_ws, size_t ws_size,
                              hipStream_t stream) {
    const float* x    = (const float*)d_in[0];
    const float* w    = (const float*)d_in[1];
    // d_in[2] (mask) intentionally unused: recomputed exactly from weight.
    const float* bias = (const float*)d_in[3];
    float* out        = (float*)d_out;

    const size_t x_elems = (size_t)M_DIM * K_DIM;
    const size_t w_elems = (size_t)N_DIM * K_DIM;
    const size_t need    = (x_elems + w_elems) * sizeof(unsigned short);

    if (ws_size >= need) {
        unsigned short* xb = (unsigned short*)d_ws;
        unsigned short* wb = xb + x_elems;

        int n8 = (int)(x_elems / 8);
        cvt_x_kernel<<<(n8 + 255) / 256, 256, 0, stream>>>(x, xb, n8);
        int ng = (int)(w_elems / 4);
        cvt_w_kernel<<<(ng + 255) / 256, 256, 0, stream>>>(w, wb, ng);

        dim3 grid((M_DIM / BM) * (N_DIM / BN));   // 16 * 64 = 1024
        gemm_bt_kernel<<<grid, 512, 0, stream>>>(xb, wb, bias, out);
    } else {
        dim3 grid(N_DIM, M_DIM / 256);
        naive_kernel<<<grid, 256, 0, stream>>>(x, w, bias, out);
    }
}